// Round 1
// baseline (2130.852 us; speedup 1.0000x reference)
//
#include <hip/hip_runtime.h>

typedef __bf16 bf16x8 __attribute__((ext_vector_type(8)));
typedef float f32x4 __attribute__((ext_vector_type(4)));

__device__ __forceinline__ float bf2f(unsigned short u) {
  return __uint_as_float(((unsigned)u) << 16);
}
__device__ __forceinline__ unsigned short f2bf(float f) {
  unsigned u = __float_as_uint(f);
  return (unsigned short)((u + 0x7fffu + ((u >> 16) & 1u)) >> 16);
}
__device__ __forceinline__ unsigned pack2(float a, float b) {
  return (unsigned)f2bf(a) | ((unsigned)f2bf(b) << 16);
}

// ---------------- lambda scalar ----------------
__global__ void lambda_kernel(const float* __restrict__ lq1, const float* __restrict__ lq2,
                              const float* __restrict__ lk1, const float* __restrict__ lk2,
                              float* __restrict__ out, float lam_init) {
  int l = threadIdx.x;
  float p1 = lq1[l] * lk1[l];
  float p2 = lq2[l] * lk2[l];
  #pragma unroll
  for (int off = 32; off; off >>= 1) {
    p1 += __shfl_xor(p1, off);
    p2 += __shfl_xor(p2, off);
  }
  if (l == 0) out[0] = expf(p1) - expf(p2) + lam_init;
}

// ---------------- GEMM: C[m][n] = sum_k A[m][k] * Bw[n][k] ----------------
// bf16 MFMA 16x16x32; 128x128 tile, BK=32, 4 waves (2x2), 4x4 frags/wave.
template <typename T>
__device__ __forceinline__ void stage16(const T* __restrict__ g, unsigned short* l) {
  if constexpr (sizeof(T) == 4) {
    #pragma unroll
    for (int p = 0; p < 4; ++p) {
      float4 v = reinterpret_cast<const float4*>(g)[p];
      uint2 pk;
      pk.x = pack2(v.x, v.y);
      pk.y = pack2(v.z, v.w);
      *reinterpret_cast<uint2*>(l + p * 4) = pk;
    }
  } else {
    const uint4* s = reinterpret_cast<const uint4*>(g);
    uint4 a = s[0], b = s[1];
    *reinterpret_cast<uint4*>(l) = a;
    *reinterpret_cast<uint4*>(l + 8) = b;
  }
}

template <typename AT, typename BT, typename OT>
__global__ __launch_bounds__(256)
void gemm_bt(const AT* __restrict__ A, const BT* __restrict__ Bw, OT* __restrict__ C,
             int M, int N, int K) {
  __shared__ __align__(16) unsigned short As[128 * 32];
  __shared__ __align__(16) unsigned short Bs[128 * 32];
  const int tid = threadIdx.x;
  const int bm = blockIdx.x * 128, bn = blockIdx.y * 128;
  const int lane = tid & 63, wave = tid >> 6;
  const int wm = (wave >> 1) * 64, wn = (wave & 1) * 64;
  const int srow = tid >> 1, shalf = (tid & 1) * 16;
  const int kf = (lane >> 4) * 8, rr = lane & 15;
  f32x4 acc[4][4] = {};
  for (int kt = 0; kt < K; kt += 32) {
    __syncthreads();
    stage16(&A[(long)(bm + srow) * K + kt + shalf], &As[srow * 32 + shalf]);
    stage16(&Bw[(long)(bn + srow) * K + kt + shalf], &Bs[srow * 32 + shalf]);
    __syncthreads();
    bf16x8 af[4], bq[4];
    #pragma unroll
    for (int i = 0; i < 4; ++i)
      af[i] = *reinterpret_cast<const bf16x8*>(&As[(wm + i * 16 + rr) * 32 + kf]);
    #pragma unroll
    for (int j = 0; j < 4; ++j)
      bq[j] = *reinterpret_cast<const bf16x8*>(&Bs[(wn + j * 16 + rr) * 32 + kf]);
    #pragma unroll
    for (int i = 0; i < 4; ++i)
      #pragma unroll
      for (int j = 0; j < 4; ++j)
        acc[i][j] = __builtin_amdgcn_mfma_f32_16x16x32_bf16(af[i], bq[j], acc[i][j], 0, 0, 0);
  }
  const int r0 = (lane >> 4) * 4, c0 = lane & 15;
  #pragma unroll
  for (int i = 0; i < 4; ++i)
    #pragma unroll
    for (int j = 0; j < 4; ++j) {
      #pragma unroll
      for (int r = 0; r < 4; ++r) {
        long row = bm + wm + i * 16 + r0 + r;
        long col = bn + wn + j * 16 + c0;
        float v = acc[i][j][r];
        if constexpr (sizeof(OT) == 2) C[row * N + col] = f2bf(v);
        else                           C[row * N + col] = v;
      }
    }
}

// ---------------- RoPE (+optional rel_pos pre-scale), with transpose ----------------
// in : raw proj bf16 [(b*1024+t)*2048 + hp*64 + d]   (b,t,hp,d)
// out: bf16 [((b*32+hp)*1024+t)*64 + d]              (b,hp,t,d)
__global__ __launch_bounds__(256) void rope_kernel(const unsigned short* __restrict__ raw,
                                                   const float* __restrict__ rel,
                                                   unsigned short* __restrict__ out,
                                                   int use_rel) {
  int idx = blockIdx.x * 256 + threadIdx.x;  // 2^21 total
  int i = idx & 31;
  int t = (idx >> 5) & 1023;
  int hp = (idx >> 15) & 31;
  int b = idx >> 20;
  int src = (b * 1024 + t) * 2048 + hp * 64 + 2 * i;
  unsigned pair = *reinterpret_cast<const unsigned*>(&raw[src]);
  float x1 = __uint_as_float(pair << 16);
  float x2 = __uint_as_float(pair & 0xffff0000u);
  if (use_rel) {
    x1 *= rel[t * 64 + 2 * i];
    x2 *= rel[t * 64 + 2 * i + 1];
  }
  float inv = expf(-0.28782313662425574f * (float)i);  // 10000^(-2i/64)
  float ang = (float)t * inv;
  float s, c;
  sincosf(ang, &s, &c);
  float r1 = x1 * c - x2 * s;
  float r2 = x1 * s + x2 * c;
  int dst = ((b * 32 + hp) * 1024 + t) * 64 + 2 * i;
  *reinterpret_cast<unsigned*>(&out[dst]) = pack2(r1, r2);
}

// ---------------- differential flash attention + fused sub-LN ----------------
#define QB 16
#define KB 64
__global__ __launch_bounds__(256) void attn_kernel(
    const unsigned short* __restrict__ Qa,  // (B,32,T,64) bf16
    const unsigned short* __restrict__ Ka,  // (B,32,T,64) bf16
    const unsigned short* __restrict__ Vr,  // (B,T,2048) bf16 raw-proj layout
    const float* __restrict__ lam_p,
    const float* __restrict__ subln,        // 128
    unsigned short* __restrict__ O) {       // (B,T,2048) bf16
  const int qt = blockIdx.x, h = blockIdx.y, b = blockIdx.z;
  const int tid = threadIdx.x;
  __shared__ __align__(16) float Qs[2][QB][64];
  __shared__ __align__(16) unsigned short Ks[2][KB][64];
  __shared__ __align__(16) unsigned short Vs[KB][128];
  __shared__ float S[2][QB][KB];
  __shared__ float mrow[2][QB], lrow[2][QB], rrow[2][QB];

  const float lam = lam_p[0];
  const int q0 = qt * QB;

  // load Q tiles (both sub-heads), pre-scaled by 1/sqrt(D)=1/8
  for (int e = tid; e < 2 * QB * 64; e += 256) {
    int hh = e >> 10;
    int qq = (e >> 6) & 15;
    int d = e & 63;
    float v = bf2f(Qa[((long)(b * 32 + 2 * h + hh) * 1024 + q0 + qq) * 64 + d]);
    Qs[hh][qq][d] = v * 0.125f;
  }
  if (tid < 2 * QB) {
    mrow[tid >> 4][tid & 15] = -1e30f;
    lrow[tid >> 4][tid & 15] = 0.f;
  }

  float o1[8], o2[8];
  #pragma unroll
  for (int j = 0; j < 8; ++j) { o1[j] = 0.f; o2[j] = 0.f; }
  const int oq = tid >> 4, oc = (tid & 15) * 8;

  const int ntiles = (q0 + QB - 1) / KB + 1;
  for (int tile = 0; tile < ntiles; ++tile) {
    const int k0 = tile * KB;
    __syncthreads();  // protect LDS from previous iteration's readers
    // stage K (2 heads x 64 x 64) as uint2
    for (int e = tid; e < 2 * KB * 16; e += 256) {
      int hh = e >> 10;
      int kk = (e >> 4) & 63;
      int dq = (e & 15) * 4;
      *reinterpret_cast<uint2*>(&Ks[hh][kk][dq]) = *reinterpret_cast<const uint2*>(
          &Ka[((long)(b * 32 + 2 * h + hh) * 1024 + k0 + kk) * 64 + dq]);
    }
    // stage V (64 x 128)
    for (int e = tid; e < KB * 32; e += 256) {
      int kk = e >> 5;
      int cq = (e & 31) * 4;
      *reinterpret_cast<uint2*>(&Vs[kk][cq]) = *reinterpret_cast<const uint2*>(
          &Vr[(long)(b * 1024 + k0 + kk) * 2048 + h * 128 + cq]);
    }
    __syncthreads();
    // scores: thread -> (sq, 4 consecutive ks), both heads
    {
      const int sq = tid >> 4;
      const int sk = (tid & 15) * 4;
      const int qglob = q0 + sq;
      float sa[4] = {0.f, 0.f, 0.f, 0.f}, sb[4] = {0.f, 0.f, 0.f, 0.f};
      for (int d = 0; d < 64; d += 4) {
        float4 qa = *reinterpret_cast<const float4*>(&Qs[0][sq][d]);
        float4 qb = *reinterpret_cast<const float4*>(&Qs[1][sq][d]);
        #pragma unroll
        for (int kk = 0; kk < 4; ++kk) {
          uint2 ka = *reinterpret_cast<const uint2*>(&Ks[0][sk + kk][d]);
          uint2 kb = *reinterpret_cast<const uint2*>(&Ks[1][sk + kk][d]);
          sa[kk] += qa.x * __uint_as_float(ka.x << 16) + qa.y * __uint_as_float(ka.x & 0xffff0000u) +
                    qa.z * __uint_as_float(ka.y << 16) + qa.w * __uint_as_float(ka.y & 0xffff0000u);
          sb[kk] += qb.x * __uint_as_float(kb.x << 16) + qb.y * __uint_as_float(kb.x & 0xffff0000u) +
                    qb.z * __uint_as_float(kb.y << 16) + qb.w * __uint_as_float(kb.y & 0xffff0000u);
        }
      }
      #pragma unroll
      for (int kk = 0; kk < 4; ++kk) {
        bool msk = (k0 + sk + kk) > qglob;
        S[0][sq][sk + kk] = msk ? -1e30f : sa[kk];
        S[1][sq][sk + kk] = msk ? -1e30f : sb[kk];
      }
    }
    __syncthreads();
    // online softmax per row: 32 rows, 8 threads each
    {
      const int row = tid >> 3, sub = tid & 7;
      const int hh = row >> 4, qq = row & 15;
      float mx = -1e30f;
      for (int kk = sub; kk < KB; kk += 8) mx = fmaxf(mx, S[hh][qq][kk]);
      #pragma unroll
      for (int off = 4; off; off >>= 1) mx = fmaxf(mx, __shfl_xor(mx, off));
      float mold = mrow[hh][qq];
      float mnew = fmaxf(mold, mx);
      float ls = 0.f;
      for (int kk = sub; kk < KB; kk += 8) {
        float p = __expf(S[hh][qq][kk] - mnew);  // masked: exp(-1e30-m) == 0
        S[hh][qq][kk] = p;
        ls += p;
      }
      #pragma unroll
      for (int off = 4; off; off >>= 1) ls += __shfl_xor(ls, off);
      if (sub == 0) {
        float resc = __expf(mold - mnew);
        lrow[hh][qq] = lrow[hh][qq] * resc + ls;
        mrow[hh][qq] = mnew;
        rrow[hh][qq] = resc;
      }
    }
    __syncthreads();
    // PV accumulate: thread -> (oq, 8 channels)
    {
      float rA = rrow[0][oq], rB = rrow[1][oq];
      #pragma unroll
      for (int j = 0; j < 8; ++j) { o1[j] *= rA; o2[j] *= rB; }
      for (int kk = 0; kk < KB; ++kk) {
        float pA = S[0][oq][kk], pB = S[1][oq][kk];
        uint4 vv = *reinterpret_cast<const uint4*>(&Vs[kk][oc]);
        float vf[8];
        vf[0] = __uint_as_float(vv.x << 16); vf[1] = __uint_as_float(vv.x & 0xffff0000u);
        vf[2] = __uint_as_float(vv.y << 16); vf[3] = __uint_as_float(vv.y & 0xffff0000u);
        vf[4] = __uint_as_float(vv.z << 16); vf[5] = __uint_as_float(vv.z & 0xffff0000u);
        vf[6] = __uint_as_float(vv.w << 16); vf[7] = __uint_as_float(vv.w & 0xffff0000u);
        #pragma unroll
        for (int j = 0; j < 8; ++j) { o1[j] += pA * vf[j]; o2[j] += pB * vf[j]; }
      }
    }
  }
  // epilogue: combine, RMS-norm over 128, subln scale, store bf16
  float lA = lrow[0][oq], lB = lrow[1][oq];
  float iA = 1.f / lA, iB = lam / lB;
  float at[8], ss = 0.f;
  #pragma unroll
  for (int j = 0; j < 8; ++j) {
    at[j] = o1[j] * iA - o2[j] * iB;
    ss += at[j] * at[j];
  }
  #pragma unroll
  for (int off = 8; off; off >>= 1) ss += __shfl_xor(ss, off);
  float scale = rsqrtf(ss * (1.f / 128.f) + 1e-5f);
  float vj[8];
  #pragma unroll
  for (int j = 0; j < 8; ++j) vj[j] = at[j] * scale * subln[oc + j];
  uint4 ow;
  ow.x = pack2(vj[0], vj[1]);
  ow.y = pack2(vj[2], vj[3]);
  ow.z = pack2(vj[4], vj[5]);
  ow.w = pack2(vj[6], vj[7]);
  const int qglob = q0 + oq;
  *reinterpret_cast<uint4*>(&O[(long)(b * 1024 + qglob) * 2048 + h * 128 + oc]) = ow;
}

extern "C" void kernel_launch(void* const* d_in, const int* in_sizes, int n_in,
                              void* d_out, int out_size, void* d_ws, size_t ws_size,
                              hipStream_t stream) {
  (void)in_sizes; (void)n_in; (void)out_size; (void)ws_size;
  const float* x    = (const float*)d_in[0];
  const float* rel  = (const float*)d_in[1];
  const float* wq   = (const float*)d_in[2];
  const float* wk   = (const float*)d_in[3];
  const float* wv   = (const float*)d_in[4];
  const float* lq1  = (const float*)d_in[5];
  const float* lq2  = (const float*)d_in[6];
  const float* lk1  = (const float*)d_in[7];
  const float* lk2  = (const float*)d_in[8];
  const float* subw = (const float*)d_in[9];
  const float* wo   = (const float*)d_in[10];
  float* out = (float*)d_out;

  char* ws = (char*)d_ws;
  const size_t SZ = (size_t)2048 * 2048 * 2;  // 8 MB (bf16 2048x2048)
  unsigned short* qraw = (unsigned short*)(ws);
  unsigned short* kraw = (unsigned short*)(ws + SZ);
  unsigned short* vraw = (unsigned short*)(ws + 2 * SZ);
  unsigned short* qatt = (unsigned short*)(ws + 3 * SZ);
  unsigned short* katt = (unsigned short*)(ws + 4 * SZ);
  float* lamb          = (float*)(ws + 5 * SZ);
  unsigned short* aout = qraw;  // qraw is dead after rope(q)

  // LAMBDA_INIT = 0.8 - 0.6*exp(-0.3*12)
  lambda_kernel<<<1, 64, 0, stream>>>(lq1, lq2, lk1, lk2, lamb, 0.7836057665316245f);

  dim3 gg(16, 16);
  gemm_bt<float, float, unsigned short><<<gg, 256, 0, stream>>>(x, wq, qraw, 2048, 2048, 2048);
  gemm_bt<float, float, unsigned short><<<gg, 256, 0, stream>>>(x, wk, kraw, 2048, 2048, 2048);
  gemm_bt<float, float, unsigned short><<<gg, 256, 0, stream>>>(x, wv, vraw, 2048, 2048, 2048);

  rope_kernel<<<8192, 256, 0, stream>>>(qraw, rel, qatt, 0);
  rope_kernel<<<8192, 256, 0, stream>>>(kraw, rel, katt, 1);

  attn_kernel<<<dim3(64, 16, 2), 256, 0, stream>>>(qatt, katt, vraw, lamb, subw, aout);

  gemm_bt<unsigned short, float, float><<<gg, 256, 0, stream>>>(aout, wo, out, 2048, 2048, 2048);
}